// Round 9
// baseline (295.506 us; speedup 1.0000x reference)
//
#include <hip/hip_runtime.h>
#include <hip/hip_bf16.h>
#include <cmath>

#define USER_NUM 52643
#define ITEM_NUM 91599
#define NNODE (USER_NUM + ITEM_NUM)   // 144242
#define DDIM 64
#define NBUCK 564                     // ceil(NNODE/256)
#define EPB 8192                      // edges per staging block
#define BCAP 8192                     // max edges per bucket (mean ~4.9K, 47-sigma margin)

typedef unsigned int uint32;

using bf16x8 = __attribute__((ext_vector_type(8))) short;
using f32x4  = __attribute__((ext_vector_type(4))) float;

__device__ __forceinline__ uint32 f2bf(float f) {
    uint32 u = __float_as_uint(f);
    u += 0x7fffu + ((u >> 16) & 1u);   // round-to-nearest-even
    return u >> 16;
}
__device__ __forceinline__ uint32 packbf(float lo, float hi) {
    return (f2bf(hi) << 16) | f2bf(lo);
}

// ---------------- small utility kernels ----------------

__global__ void init_loss_kernel(float* __restrict__ out, int loss_idx) {
    if (threadIdx.x == 0) out[loss_idx] = 0.0f;
}

// ---------------- bucketed CSR build (all global writes dense) ----------------

// K2: per-block bucket histogram -> blkcnt[block][NBUCK]
__global__ __launch_bounds__(1024) void bucket_count_kernel(
    const int* __restrict__ rows, int* __restrict__ blkcnt, int E)
{
    __shared__ int cnt[NBUCK];
    int t = threadIdx.x;
    for (int i = t; i < NBUCK; i += 1024) cnt[i] = 0;
    __syncthreads();
    int base = blockIdx.x * EPB;
    for (int i = t; i < EPB; i += 1024) {
        int e = base + i;
        if (e < E) atomicAdd(&cnt[rows[e] >> 8], 1);
    }
    __syncthreads();
    for (int i = t; i < NBUCK; i += 1024) blkcnt[blockIdx.x * NBUCK + i] = cnt[i];
}

// K3: one block per bucket; exclusive scan of blkcnt over blocks; totals[b]
__global__ __launch_bounds__(256) void bucket_block_scan_kernel(
    int* __restrict__ blkcnt, int* __restrict__ totals, int nblocks)
{
    __shared__ int wsum[4];
    int b = blockIdx.x, t = threadIdx.x;
    int lane = t & 63, wid = t >> 6;
    int c = (t < nblocks) ? blkcnt[t * NBUCK + b] : 0;
    int v = c;
    #pragma unroll
    for (int d = 1; d < 64; d <<= 1) {
        int src = (lane >= d) ? (lane - d) : lane;
        int tmp = __shfl(v, src);
        v += (lane >= d) ? tmp : 0;
    }
    if (lane == 63) wsum[wid] = v;
    __syncthreads();
    int woff = 0;
    for (int w = 0; w < wid; ++w) woff += wsum[w];
    int excl = woff + v - c;
    if (t < nblocks) blkcnt[t * NBUCK + b] = excl;
    if (t == 255) totals[b] = excl + c;
}

// K4: exclusive scan of totals -> bucket_off (= row_ptr at bucket starts)
__global__ __launch_bounds__(1024) void bucket_off_kernel(
    const int* __restrict__ totals, int* __restrict__ bucket_off,
    int* __restrict__ row_ptr, int E)
{
    __shared__ int s[1024];
    int t = threadIdx.x;
    int v = (t < NBUCK) ? totals[t] : 0;
    s[t] = v;
    __syncthreads();
    #pragma unroll
    for (int d = 1; d < 1024; d <<= 1) {
        int add = (t >= d) ? s[t - d] : 0;
        __syncthreads();
        s[t] += add;
        __syncthreads();
    }
    if (t < NBUCK) bucket_off[t] = s[t] - v;
    if (t == 0) { bucket_off[NBUCK] = E; row_ptr[NNODE] = E; }
}

// K5: stage edges into bucket slices, packed (r&255)<<18 | col (dense-ish writes)
__global__ __launch_bounds__(1024) void stage_kernel(
    const int* __restrict__ rows, const int* __restrict__ cols,
    const int* __restrict__ blkcnt, const int* __restrict__ bucket_off,
    uint32* __restrict__ staged, int E)
{
    __shared__ int cnt[NBUCK];
    __shared__ int basel[NBUCK];
    int t = threadIdx.x;
    for (int i = t; i < NBUCK; i += 1024) {
        cnt[i] = 0;
        basel[i] = bucket_off[i] + blkcnt[blockIdx.x * NBUCK + i];
    }
    __syncthreads();
    int base = blockIdx.x * EPB;
    for (int i = t; i < EPB; i += 1024) {
        int e = base + i;
        if (e < E) {
            int r = rows[e];
            int bkt = r >> 8;
            int rank = atomicAdd(&cnt[bkt], 1);
            staged[basel[bkt] + rank] = ((uint32)(r & 255) << 18) | (uint32)cols[e];
        }
    }
}

// K6: one block per bucket: derive degrees (-> row_ptr, dinv, wout, sback),
// LDS-order the cols, stream out csr_col densely.
__global__ __launch_bounds__(256) void build_kernel(
    const uint32* __restrict__ staged, const int* __restrict__ bucket_off,
    int* __restrict__ row_ptr, int* __restrict__ csr_col,
    float* __restrict__ dinv, float* __restrict__ wout, float* __restrict__ sback)
{
    __shared__ int cnt[256];
    __shared__ int off[256];
    __shared__ int wsum[4];
    __shared__ int colbuf[BCAP];
    int b = blockIdx.x, t = threadIdx.x;
    int lane = t & 63, wid = t >> 6;
    int eoff = bucket_off[b];
    int ecnt = bucket_off[b + 1] - eoff;

    cnt[t] = 0;
    __syncthreads();
    for (int i = t; i < ecnt; i += 256) atomicAdd(&cnt[staged[eoff + i] >> 18], 1);
    __syncthreads();

    int c = cnt[t];
    int v = c;
    #pragma unroll
    for (int d = 1; d < 64; d <<= 1) {
        int src = (lane >= d) ? (lane - d) : lane;
        int tmp = __shfl(v, src);
        v += (lane >= d) ? tmp : 0;
    }
    if (lane == 63) wsum[wid] = v;
    __syncthreads();
    int woff = 0;
    for (int w = 0; w < wid; ++w) woff += wsum[w];
    int excl = woff + v - c;
    off[t] = excl;

    int node = b * 256 + t;
    if (node < NNODE) {
        row_ptr[node] = eoff + excl;
        float df = (float)c;
        float dv = (c > 0) ? (1.0f / sqrtf(df)) : 0.0f;
        dinv[node]  = dv;
        wout[node]  = (c > 0) ? dv : 1.0f;
        sback[node] = (c > 0) ? sqrtf(df) : 1.0f;
    }
    __syncthreads();
    cnt[t] = 0;
    __syncthreads();
    for (int i = t; i < ecnt; i += 256) {
        uint32 w = staged[eoff + i];
        int rl = w >> 18;
        int rank = atomicAdd(&cnt[rl], 1);
        colbuf[off[rl] + rank] = (int)(w & 0x3FFFFu);
    }
    __syncthreads();
    for (int i = t; i < ecnt; i += 256) csr_col[eoff + i] = colbuf[i];
}

// pack layer-1 table: per node, uint2 per dim-pair = (bf16pair(w*x0, w*x1),
// bf16pair(w*x0^2, w*x1^2)), w = wout. Zero dummy row NNODE in y1b AND y1b2.
__global__ void pack1_kernel(const float* __restrict__ eu, const float* __restrict__ ei,
                             const float* __restrict__ wout,
                             uint2* __restrict__ y1b, uint2* __restrict__ y1b2) {
    int t = blockIdx.x * 256 + threadIdx.x;     // t = n*32 + d2
    int n = t >> 5, d2 = t & 31;
    if (n > NNODE) return;
    if (n == NNODE) { y1b[t] = make_uint2(0, 0); y1b2[t] = make_uint2(0, 0); return; }
    const float* xp = (n < USER_NUM) ? (eu + ((size_t)n << 6))
                                     : (ei + (((size_t)n - USER_NUM) << 6));
    float2 x2 = *(const float2*)(xp + 2 * d2);
    float wv = wout[n];
    y1b[t] = make_uint2(packbf(wv * x2.x, wv * x2.y),
                        packbf(wv * x2.x * x2.x, wv * x2.y * x2.y));
}

// ---------------- fused GNN layer ----------------
// Gather: lane l = dim-pair (l&31) of edge parity (l>>5); ONE 8B uint2 gather per
// edge gives both y (=w*x) and z (=w*x^2) pairs -> p2 is plain adds, no sback dep.
// Unroll 8 (16 edges/k-step, 8 loads in flight). Identity via own table row *sback
// (exact: wout*sback==1). Epilogue: MFMA, writes packed y+z table.

__global__ __launch_bounds__(256, 4) void gnn_layer_kernel(
    const uint2* __restrict__ ytab,
    const int* __restrict__ row_ptr, const int* __restrict__ csr_col,
    const float* __restrict__ sback, const float* __restrict__ dinv,
    const float* __restrict__ wout,
    const float* __restrict__ W, const float* __restrict__ b,
    const float* __restrict__ Wi, const float* __restrict__ bi,
    uint2* __restrict__ otab)
{
    __shared__ unsigned short P1s[64 * 64];   // [row][dim] bf16, byte-col ^ ((row&7)<<4)
    __shared__ unsigned short P2s[64 * 64];

    int tid = threadIdx.x;
    int lane = tid & 63;
    int wid = tid >> 6;
    int h = lane >> 5;        // edge parity
    int d2 = lane & 31;       // dim-pair index
    int base = blockIdx.x * 64;

    // ---- gather phase: 16 rows per wave ----
    for (int i = 0; i < 16; ++i) {
        int rr = wid * 16 + i;            // row-local 0..63
        int row = base + rr;
        float p1l = 0.f, p1h = 0.f, p2l = 0.f, p2h = 0.f;
        if (row < NNODE) {
            int e0 = row_ptr[row], e1 = row_ptr[row + 1];
            float aA = 0.f, aB = 0.f, aC = 0.f, aD = 0.f;
            for (int eb = e0; eb < e1; eb += 64) {
                int e = eb + lane;
                int c = NNODE;
                if (e < e1) c = csr_col[e];          // coalesced 4B
                int nn = min(64, e1 - eb);
                for (int k = 0; k < nn; k += 16) {
                    uint2 g[8];
                    #pragma unroll
                    for (int u = 0; u < 8; ++u) {
                        int cc = __shfl(c, k + 2 * u + h);   // dummies -> row NNODE (zeros)
                        g[u] = ytab[(size_t)cc * 32 + d2];   // 8B: y-pair + z-pair
                    }
                    #pragma unroll
                    for (int u = 0; u < 8; ++u) {
                        aA += __uint_as_float(g[u].x << 16);
                        aB += __uint_as_float(g[u].x & 0xffff0000u);
                        aC += __uint_as_float(g[u].y << 16);
                        aD += __uint_as_float(g[u].y & 0xffff0000u);
                    }
                }
            }
            // combine edge parities
            aA += __shfl_xor(aA, 32); aB += __shfl_xor(aB, 32);
            aC += __shfl_xor(aC, 32); aD += __shfl_xor(aD, 32);
            float dv = dinv[row];
            float sb = sback[row];
            uint2 wy = ytab[(size_t)row * 32 + d2];
            float xl = __uint_as_float(wy.x << 16) * sb;          // x = y*sback (exact scale)
            float xh = __uint_as_float(wy.x & 0xffff0000u) * sb;
            p1l = fmaf(dv, aA, xl);   // (L+I)@x
            p1h = fmaf(dv, aB, xh);
            p2l = dv * aC;            // L@(x*x)
            p2h = dv * aD;
        }
        if (h == 0) {
            int cb = (4 * d2) ^ ((rr & 7) << 4);
            *(uint32*)&P1s[rr * 64 + (cb >> 1)] = packbf(p1l, p1h);
            *(uint32*)&P2s[rr * 64 + (cb >> 1)] = packbf(p2l, p2h);
        }
    }
    __syncthreads();

    // ---- MFMA phase: wave wid computes cols [16*wid, 16*wid+16) for all 64 rows ----
    int l15 = lane & 15;
    int l4  = lane >> 4;
    int n0  = wid * 16;

    bf16x8 wf[2], wif[2];
    #pragma unroll
    for (int kt = 0; kt < 2; ++kt) {
        const float* wr  = W  + (size_t)(n0 + l15) * 64 + kt * 32 + l4 * 8;
        const float* wir = Wi + (size_t)(n0 + l15) * 64 + kt * 32 + l4 * 8;
        f32x4 a0 = *(const f32x4*)wr;
        f32x4 a1 = *(const f32x4*)(wr + 4);
        f32x4 c0 = *(const f32x4*)wir;
        f32x4 c1 = *(const f32x4*)(wir + 4);
        bf16x8 t0, t1;
        #pragma unroll
        for (int j = 0; j < 4; ++j) {
            t0[j]     = (short)f2bf(a0[j]);
            t0[j + 4] = (short)f2bf(a1[j]);
            t1[j]     = (short)f2bf(c0[j]);
            t1[j + 4] = (short)f2bf(c1[j]);
        }
        wf[kt]  = t0;
        wif[kt] = t1;
    }
    float bias_v = b[n0 + l15] + bi[n0 + l15];

    f32x4 acc0 = {0.f,0.f,0.f,0.f}, acc1v = {0.f,0.f,0.f,0.f};
    f32x4 acc2v = {0.f,0.f,0.f,0.f}, acc3 = {0.f,0.f,0.f,0.f};
    f32x4* accp[4] = {&acc0, &acc1v, &acc2v, &acc3};

    #pragma unroll
    for (int mt = 0; mt < 4; ++mt) {
        #pragma unroll
        for (int kt = 0; kt < 2; ++kt) {
            int rl = mt * 16 + l15;
            int cb = (kt * 64 + l4 * 16) ^ ((rl & 7) << 4);
            int idx = rl * 64 + (cb >> 1);
            bf16x8 a1f = *(const bf16x8*)&P1s[idx];
            bf16x8 a2f = *(const bf16x8*)&P2s[idx];
            *accp[mt] = __builtin_amdgcn_mfma_f32_16x16x32_bf16(a1f, wf[kt],  *accp[mt], 0, 0, 0);
            *accp[mt] = __builtin_amdgcn_mfma_f32_16x16x32_bf16(a2f, wif[kt], *accp[mt], 0, 0, 0);
        }
    }

    // C layout: col = lane&15, row = (lane>>4)*4 + j (+ mt*16). Write packed y+z table.
    #pragma unroll
    for (int mt = 0; mt < 4; ++mt) {
        #pragma unroll
        for (int j = 0; j < 4; ++j) {
            int r = base + mt * 16 + l4 * 4 + j;
            float o = fmaxf((*accp[mt])[j] + bias_v, 0.0f);
            float wsc = (r < NNODE) ? wout[r] : 0.0f;
            float oy = o * wsc;          // wout * o
            float oz = oy * o;           // wout * o^2
            float oyn = __shfl_xor(oy, 1);
            float ozn = __shfl_xor(oz, 1);
            if (((l15 & 1) == 0) && r < NNODE)
                otab[(size_t)r * 32 + ((n0 + l15) >> 1)] =
                    make_uint2(packbf(oy, oyn), packbf(oz, ozn));
        }
    }
}

// ---------------- scoring + loss ----------------
// Each wave grid-strides over samples (8 per wave); one atomicAdd per block.

__global__ __launch_bounds__(256) void score_kernel(
    const int* __restrict__ user, const int* __restrict__ item_i,
    const int* __restrict__ item_j,
    const float* __restrict__ eu, const float* __restrict__ ei,
    const uint32* __restrict__ y1b2, const uint32* __restrict__ y2b,
    const float* __restrict__ sback,
    float* __restrict__ out, int B, int nwaves)
{
    int tid = threadIdx.x;
    int lane = tid & 63;
    int wv = tid >> 6;
    int gw = blockIdx.x * 4 + wv;
    int h = lane >> 5, d2 = lane & 31;

    float spacc = 0.0f;
    for (int w = gw; w < B; w += nwaves) {
        int u  = user[w];
        int i0 = item_i[w];
        int j0 = item_j[w];
        int ii = USER_NUM + i0;
        int jj = USER_NUM + j0;

        float e0u = eu[(size_t)u  * DDIM + lane];
        float e0i = ei[(size_t)i0 * DDIM + lane];
        float e0j = ei[(size_t)j0 * DDIM + lane];
        float di = e0u * e0i;
        float dj = e0u * e0j;

        const uint32* tb = h ? y2b : y1b2;              // y-halves of uint2 rows
        float su = sback[u], si2 = sback[ii], sj2 = sback[jj];
        uint32 wu = tb[((size_t)u  * 32 + d2) * 2];
        uint32 wi = tb[((size_t)ii * 32 + d2) * 2];
        uint32 wj = tb[((size_t)jj * 32 + d2) * 2];
        float u0 = __uint_as_float(wu << 16) * su,   u1 = __uint_as_float(wu & 0xffff0000u) * su;
        float i0f = __uint_as_float(wi << 16) * si2, i1f = __uint_as_float(wi & 0xffff0000u) * si2;
        float j0f = __uint_as_float(wj << 16) * sj2, j1f = __uint_as_float(wj & 0xffff0000u) * sj2;
        di += u0 * i0f + u1 * i1f;
        dj += u0 * j0f + u1 * j1f;

        for (int off = 32; off; off >>= 1) {
            di += __shfl_xor(di, off);
            dj += __shfl_xor(dj, off);
        }
        if (lane == 0) {
            out[w] = di;
            out[B + w] = dj;
            float x = di - dj;
            spacc += fmaxf(-x, 0.0f) + log1pf(expf(-fabsf(x)));   // softplus(-x)
        }
    }

    __shared__ float sred[4];
    if (lane == 0) sred[wv] = spacc;
    __syncthreads();
    if (tid == 0)
        atomicAdd(&out[2 * B], sred[0] + sred[1] + sred[2] + sred[3]);
}

// ---------------- launch ----------------

extern "C" void kernel_launch(void* const* d_in, const int* in_sizes, int n_in,
                              void* d_out, int out_size, void* d_ws, size_t ws_size,
                              hipStream_t stream) {
    const int*   user       = (const int*)d_in[0];
    const int*   item_i     = (const int*)d_in[1];
    const int*   item_j     = (const int*)d_in[2];
    const int*   rows       = (const int*)d_in[3];
    const int*   cols       = (const int*)d_in[4];
    const float* embed_user = (const float*)d_in[6];
    const float* embed_item = (const float*)d_in[7];
    const float* W1  = (const float*)d_in[8];
    const float* b1  = (const float*)d_in[9];
    const float* Wi1 = (const float*)d_in[10];
    const float* bi1 = (const float*)d_in[11];
    const float* W2  = (const float*)d_in[12];
    const float* b2  = (const float*)d_in[13];
    const float* Wi2 = (const float*)d_in[14];
    const float* bi2 = (const float*)d_in[15];

    int B = in_sizes[0];
    int E = in_sizes[3];
    float* out = (float*)d_out;

    char* ws = (char*)d_ws;
    size_t off = 0;
    auto alloc = [&](size_t bytes) -> void* {
        void* p = ws + off;
        off += (bytes + 255) & ~(size_t)255;
        return p;
    };
    uint2*  y1b      = (uint2*)alloc((size_t)(NNODE + 1) * 32 * 8);   // layer-1 table (36.9 MB)
    uint2*  y1b2     = (uint2*)alloc((size_t)(NNODE + 1) * 32 * 8);   // layer-2 table
    uint2*  y2b      = y1b;                                           // alias: y1b dead after gnn1
    int*    row_ptr  = (int*)alloc((size_t)(NNODE + 1) * 4);
    int*    csr_col  = (int*)alloc((size_t)E * 4);
    uint32* staged   = (uint32*)alloc((size_t)E * 4);
    float*  dinv     = (float*)alloc((size_t)NNODE * 4);
    float*  wout     = (float*)alloc((size_t)NNODE * 4);
    float*  sback    = (float*)alloc((size_t)NNODE * 4);
    int*    totals   = (int*)alloc((size_t)NBUCK * 4);
    int*    bucket_off = (int*)alloc((size_t)(NBUCK + 1) * 4);
    int     nblocks  = (E + EPB - 1) / EPB;            // 245
    int*    blkcnt   = (int*)alloc((size_t)nblocks * NBUCK * 4);

    bucket_count_kernel<<<nblocks, 1024, 0, stream>>>(rows, blkcnt, E);
    bucket_block_scan_kernel<<<NBUCK, 256, 0, stream>>>(blkcnt, totals, nblocks);
    bucket_off_kernel<<<1, 1024, 0, stream>>>(totals, bucket_off, row_ptr, E);
    stage_kernel<<<nblocks, 1024, 0, stream>>>(rows, cols, blkcnt, bucket_off, staged, E);
    build_kernel<<<NBUCK, 256, 0, stream>>>(staged, bucket_off, row_ptr, csr_col,
                                            dinv, wout, sback);

    pack1_kernel<<<((NNODE + 1) * 32 + 255) / 256, 256, 0, stream>>>(
        embed_user, embed_item, wout, y1b, y1b2);

    const int GNNB = (NNODE + 63) / 64;   // 2254
    gnn_layer_kernel<<<GNNB, 256, 0, stream>>>(
        y1b, row_ptr, csr_col, sback, dinv, wout, W1, b1, Wi1, bi1, y1b2);
    gnn_layer_kernel<<<GNNB, 256, 0, stream>>>(
        y1b2, row_ptr, csr_col, sback, dinv, wout, W2, b2, Wi2, bi2, y2b);

    init_loss_kernel<<<1, 64, 0, stream>>>(out, 2 * B);
    const int SCORE_BLOCKS = 256;                      // 1024 waves, 8 samples each
    score_kernel<<<SCORE_BLOCKS, 256, 0, stream>>>(
        user, item_i, item_j, embed_user, embed_item,
        (const uint32*)y1b2, (const uint32*)y2b, sback,
        out, B, SCORE_BLOCKS * 4);
}

// Round 10
// 226.012 us; speedup vs baseline: 1.3075x; 1.3075x over previous
//
#include <hip/hip_runtime.h>
#include <hip/hip_bf16.h>
#include <cmath>

#define USER_NUM 52643
#define ITEM_NUM 91599
#define NNODE (USER_NUM + ITEM_NUM)   // 144242
#define DDIM 64
#define NBUCK 564                     // ceil(NNODE/256)
#define EPB 8192                      // edges per staging block
#define BCAP 8192                     // max edges per bucket (mean ~4.9K, 47-sigma margin)

typedef unsigned int uint32;

using bf16x8 = __attribute__((ext_vector_type(8))) short;
using f32x4  = __attribute__((ext_vector_type(4))) float;

__device__ __forceinline__ uint32 f2bf(float f) {
    uint32 u = __float_as_uint(f);
    u += 0x7fffu + ((u >> 16) & 1u);   // round-to-nearest-even
    return u >> 16;
}
__device__ __forceinline__ uint32 packbf(float lo, float hi) {
    return (f2bf(hi) << 16) | f2bf(lo);
}

// ---------------- small utility kernels ----------------

__global__ void init_loss_kernel(float* __restrict__ out, int loss_idx) {
    if (threadIdx.x == 0) out[loss_idx] = 0.0f;
}

// ---------------- bucketed CSR build (all global writes dense) ----------------

// K2: per-block bucket histogram -> blkcnt[block][NBUCK]
__global__ __launch_bounds__(1024) void bucket_count_kernel(
    const int* __restrict__ rows, int* __restrict__ blkcnt, int E)
{
    __shared__ int cnt[NBUCK];
    int t = threadIdx.x;
    for (int i = t; i < NBUCK; i += 1024) cnt[i] = 0;
    __syncthreads();
    int base = blockIdx.x * EPB;
    for (int i = t; i < EPB; i += 1024) {
        int e = base + i;
        if (e < E) atomicAdd(&cnt[rows[e] >> 8], 1);
    }
    __syncthreads();
    for (int i = t; i < NBUCK; i += 1024) blkcnt[blockIdx.x * NBUCK + i] = cnt[i];
}

// K3: one block per bucket; exclusive scan of blkcnt over blocks; totals[b]
__global__ __launch_bounds__(256) void bucket_block_scan_kernel(
    int* __restrict__ blkcnt, int* __restrict__ totals, int nblocks)
{
    __shared__ int wsum[4];
    int b = blockIdx.x, t = threadIdx.x;
    int lane = t & 63, wid = t >> 6;
    int c = (t < nblocks) ? blkcnt[t * NBUCK + b] : 0;
    int v = c;
    #pragma unroll
    for (int d = 1; d < 64; d <<= 1) {
        int src = (lane >= d) ? (lane - d) : lane;
        int tmp = __shfl(v, src);
        v += (lane >= d) ? tmp : 0;
    }
    if (lane == 63) wsum[wid] = v;
    __syncthreads();
    int woff = 0;
    for (int w = 0; w < wid; ++w) woff += wsum[w];
    int excl = woff + v - c;
    if (t < nblocks) blkcnt[t * NBUCK + b] = excl;
    if (t == 255) totals[b] = excl + c;
}

// K4: exclusive scan of totals -> bucket_off (= row_ptr at bucket starts)
__global__ __launch_bounds__(1024) void bucket_off_kernel(
    const int* __restrict__ totals, int* __restrict__ bucket_off,
    int* __restrict__ row_ptr, int E)
{
    __shared__ int s[1024];
    int t = threadIdx.x;
    int v = (t < NBUCK) ? totals[t] : 0;
    s[t] = v;
    __syncthreads();
    #pragma unroll
    for (int d = 1; d < 1024; d <<= 1) {
        int add = (t >= d) ? s[t - d] : 0;
        __syncthreads();
        s[t] += add;
        __syncthreads();
    }
    if (t < NBUCK) bucket_off[t] = s[t] - v;
    if (t == 0) { bucket_off[NBUCK] = E; row_ptr[NNODE] = E; }
}

// K5: stage edges into bucket slices, packed (r&255)<<18 | col (dense-ish writes)
__global__ __launch_bounds__(1024) void stage_kernel(
    const int* __restrict__ rows, const int* __restrict__ cols,
    const int* __restrict__ blkcnt, const int* __restrict__ bucket_off,
    uint32* __restrict__ staged, int E)
{
    __shared__ int cnt[NBUCK];
    __shared__ int basel[NBUCK];
    int t = threadIdx.x;
    for (int i = t; i < NBUCK; i += 1024) {
        cnt[i] = 0;
        basel[i] = bucket_off[i] + blkcnt[blockIdx.x * NBUCK + i];
    }
    __syncthreads();
    int base = blockIdx.x * EPB;
    for (int i = t; i < EPB; i += 1024) {
        int e = base + i;
        if (e < E) {
            int r = rows[e];
            int bkt = r >> 8;
            int rank = atomicAdd(&cnt[bkt], 1);
            staged[basel[bkt] + rank] = ((uint32)(r & 255) << 18) | (uint32)cols[e];
        }
    }
}

// K6: one block per bucket: derive degrees (-> row_ptr, dinv, wout, sback),
// LDS-order the cols, stream out csr_col densely.
__global__ __launch_bounds__(256) void build_kernel(
    const uint32* __restrict__ staged, const int* __restrict__ bucket_off,
    int* __restrict__ row_ptr, int* __restrict__ csr_col,
    float* __restrict__ dinv, float* __restrict__ wout, float* __restrict__ sback)
{
    __shared__ int cnt[256];
    __shared__ int off[256];
    __shared__ int wsum[4];
    __shared__ int colbuf[BCAP];
    int b = blockIdx.x, t = threadIdx.x;
    int lane = t & 63, wid = t >> 6;
    int eoff = bucket_off[b];
    int ecnt = bucket_off[b + 1] - eoff;

    cnt[t] = 0;
    __syncthreads();
    for (int i = t; i < ecnt; i += 256) atomicAdd(&cnt[staged[eoff + i] >> 18], 1);
    __syncthreads();

    int c = cnt[t];
    int v = c;
    #pragma unroll
    for (int d = 1; d < 64; d <<= 1) {
        int src = (lane >= d) ? (lane - d) : lane;
        int tmp = __shfl(v, src);
        v += (lane >= d) ? tmp : 0;
    }
    if (lane == 63) wsum[wid] = v;
    __syncthreads();
    int woff = 0;
    for (int w = 0; w < wid; ++w) woff += wsum[w];
    int excl = woff + v - c;
    off[t] = excl;

    int node = b * 256 + t;
    if (node < NNODE) {
        row_ptr[node] = eoff + excl;
        float df = (float)c;
        float dv = (c > 0) ? (1.0f / sqrtf(df)) : 0.0f;
        dinv[node]  = dv;
        wout[node]  = (c > 0) ? dv : 1.0f;
        sback[node] = (c > 0) ? sqrtf(df) : 1.0f;
    }
    __syncthreads();
    cnt[t] = 0;
    __syncthreads();
    for (int i = t; i < ecnt; i += 256) {
        uint32 w = staged[eoff + i];
        int rl = w >> 18;
        int rank = atomicAdd(&cnt[rl], 1);
        colbuf[off[rl] + rank] = (int)(w & 0x3FFFFu);
    }
    __syncthreads();
    for (int i = t; i < ecnt; i += 256) csr_col[eoff + i] = colbuf[i];
}

// pack layer-1 table: y1b[n][d2] = bf16pair(wout*x0, wout*x1); wout*sback==1 so
// identity readback x = y*sback is exact incl. deg-0. Zero dummy rows of all 3 tables.
__global__ void pack1_kernel(const float* __restrict__ eu, const float* __restrict__ ei,
                             const float* __restrict__ wout,
                             uint32* __restrict__ y1b, uint32* __restrict__ y1b2,
                             uint32* __restrict__ y2b) {
    int t = blockIdx.x * 256 + threadIdx.x;     // t = n*32 + d2
    int n = t >> 5, d2 = t & 31;
    if (n > NNODE) return;
    if (n == NNODE) { y1b[t] = 0; y1b2[t] = 0; y2b[t] = 0; return; }
    const float* xp = (n < USER_NUM) ? (eu + ((size_t)n << 6))
                                     : (ei + (((size_t)n - USER_NUM) << 6));
    float2 x2 = *(const float2*)(xp + 2 * d2);
    float wv = wout[n];
    y1b[t] = packbf(wv * x2.x, wv * x2.y);
}

// ---------------- fused GNN layer ----------------
// R8 memory structure (4B y-pair gathers + per-edge sback) + dual-row interleaved
// gather chains (2 rows per wave in flight) + wave-preloaded row_ptr + 8 blocks/CU.

__global__ __launch_bounds__(256, 8) void gnn_layer_kernel(
    const uint32* __restrict__ ytab,
    const int* __restrict__ row_ptr, const int* __restrict__ csr_col,
    const float* __restrict__ sback, const float* __restrict__ dinv,
    const float* __restrict__ wout,
    const float* __restrict__ W, const float* __restrict__ b,
    const float* __restrict__ Wi, const float* __restrict__ bi,
    uint32* __restrict__ otab)
{
    __shared__ unsigned short P1s[64 * 64];   // [row][dim] bf16, byte-col ^ ((row&7)<<4)
    __shared__ unsigned short P2s[64 * 64];

    int tid = threadIdx.x;
    int lane = tid & 63;
    int wid = tid >> 6;
    int h = lane >> 5;        // edge parity
    int d2 = lane & 31;       // dim-pair index
    int base = blockIdx.x * 64;
    int wbase = base + wid * 16;

    // preload this wave's 17 row_ptr entries (rows wbase..wbase+16, clamped)
    int rp = 0;
    if (lane <= 16) rp = row_ptr[min(wbase + lane, NNODE)];

    // ---- gather phase: 16 rows per wave, processed in interleaved pairs ----
    for (int i = 0; i < 16; i += 2) {
        int e0a = __shfl(rp, i);
        int e1a = __shfl(rp, i + 1);
        int e1b = __shfl(rp, i + 2);
        int e0b = e1a;

        float aA0 = 0.f, aB0 = 0.f, aC0 = 0.f, aD0 = 0.f;
        float aA1 = 0.f, aB1 = 0.f, aC1 = 0.f, aD1 = 0.f;

        int eba = e0a, ebb = e0b;
        while (eba < e1a || ebb < e1b) {
            int ca = NNODE, cb = NNODE;
            float sia = 0.f, sib = 0.f;
            int ea = eba + lane, eb2 = ebb + lane;
            if (ea < e1a)  { ca = csr_col[ea];  sia = sback[ca]; }
            if (eb2 < e1b) { cb = csr_col[eb2]; sib = sback[cb]; }
            int nna = min(64, e1a - eba);
            int nnb = min(64, e1b - ebb);
            int nn = max(nna, nnb);
            for (int k = 0; k < nn; k += 8) {
                uint32 ga[4], gb[4];
                float ia[4], ib[4];
                #pragma unroll
                for (int u = 0; u < 4; ++u) {
                    int idx = k + 2 * u + h;
                    int cca = __shfl(ca, idx); ia[u] = __shfl(sia, idx);
                    int ccb = __shfl(cb, idx); ib[u] = __shfl(sib, idx);
                    ga[u] = ytab[(size_t)cca * 32 + d2];   // 4B bf16-pair gather
                    gb[u] = ytab[(size_t)ccb * 32 + d2];
                }
                #pragma unroll
                for (int u = 0; u < 4; ++u) {
                    float f0 = __uint_as_float(ga[u] << 16);
                    float f1 = __uint_as_float(ga[u] & 0xffff0000u);
                    aA0 += f0; aB0 += f1;
                    aC0 = fmaf(f0 * f0, ia[u], aC0);
                    aD0 = fmaf(f1 * f1, ia[u], aD0);
                    float g0 = __uint_as_float(gb[u] << 16);
                    float g1 = __uint_as_float(gb[u] & 0xffff0000u);
                    aA1 += g0; aB1 += g1;
                    aC1 = fmaf(g0 * g0, ib[u], aC1);
                    aD1 = fmaf(g1 * g1, ib[u], aD1);
                }
            }
            eba += 64; ebb += 64;
        }

        // combine edge parities
        aA0 += __shfl_xor(aA0, 32); aB0 += __shfl_xor(aB0, 32);
        aC0 += __shfl_xor(aC0, 32); aD0 += __shfl_xor(aD0, 32);
        aA1 += __shfl_xor(aA1, 32); aB1 += __shfl_xor(aB1, 32);
        aC1 += __shfl_xor(aC1, 32); aD1 += __shfl_xor(aD1, 32);

        #pragma unroll
        for (int s = 0; s < 2; ++s) {
            int row = wbase + i + s;
            int rc = min(row, NNODE);                 // dummy row = zeros
            float dv = (row < NNODE) ? dinv[row]  : 0.f;
            float sb = (row < NNODE) ? sback[row] : 0.f;
            uint32 wy = ytab[(size_t)rc * 32 + d2];
            float xl = __uint_as_float(wy << 16) * sb;          // x = y*sback (exact)
            float xh = __uint_as_float(wy & 0xffff0000u) * sb;
            float sA = s ? aA1 : aA0, sB = s ? aB1 : aB0;
            float sC = s ? aC1 : aC0, sD = s ? aD1 : aD0;
            float p1l = fmaf(dv, sA, xl);   // (L+I)@x
            float p1h = fmaf(dv, sB, xh);
            float p2l = dv * sC;            // L@(x*x)
            float p2h = dv * sD;
            if (h == 0) {
                int rr = wid * 16 + i + s;
                int cbx = (4 * d2) ^ ((rr & 7) << 4);
                *(uint32*)&P1s[rr * 64 + (cbx >> 1)] = packbf(p1l, p1h);
                *(uint32*)&P2s[rr * 64 + (cbx >> 1)] = packbf(p2l, p2h);
            }
        }
    }
    __syncthreads();

    // ---- MFMA phase: wave wid computes cols [16*wid, 16*wid+16) for all 64 rows ----
    int l15 = lane & 15;
    int l4  = lane >> 4;
    int n0  = wid * 16;

    bf16x8 wf[2], wif[2];
    #pragma unroll
    for (int kt = 0; kt < 2; ++kt) {
        const float* wr  = W  + (size_t)(n0 + l15) * 64 + kt * 32 + l4 * 8;
        const float* wir = Wi + (size_t)(n0 + l15) * 64 + kt * 32 + l4 * 8;
        f32x4 a0 = *(const f32x4*)wr;
        f32x4 a1 = *(const f32x4*)(wr + 4);
        f32x4 c0 = *(const f32x4*)wir;
        f32x4 c1 = *(const f32x4*)(wir + 4);
        bf16x8 t0, t1;
        #pragma unroll
        for (int j = 0; j < 4; ++j) {
            t0[j]     = (short)f2bf(a0[j]);
            t0[j + 4] = (short)f2bf(a1[j]);
            t1[j]     = (short)f2bf(c0[j]);
            t1[j + 4] = (short)f2bf(c1[j]);
        }
        wf[kt]  = t0;
        wif[kt] = t1;
    }
    float bias_v = b[n0 + l15] + bi[n0 + l15];

    f32x4 acc0 = {0.f,0.f,0.f,0.f}, acc1v = {0.f,0.f,0.f,0.f};
    f32x4 acc2v = {0.f,0.f,0.f,0.f}, acc3 = {0.f,0.f,0.f,0.f};
    f32x4* accp[4] = {&acc0, &acc1v, &acc2v, &acc3};

    #pragma unroll
    for (int mt = 0; mt < 4; ++mt) {
        #pragma unroll
        for (int kt = 0; kt < 2; ++kt) {
            int rl = mt * 16 + l15;
            int cbx = (kt * 64 + l4 * 16) ^ ((rl & 7) << 4);
            int idx = rl * 64 + (cbx >> 1);
            bf16x8 a1f = *(const bf16x8*)&P1s[idx];
            bf16x8 a2f = *(const bf16x8*)&P2s[idx];
            *accp[mt] = __builtin_amdgcn_mfma_f32_16x16x32_bf16(a1f, wf[kt],  *accp[mt], 0, 0, 0);
            *accp[mt] = __builtin_amdgcn_mfma_f32_16x16x32_bf16(a2f, wif[kt], *accp[mt], 0, 0, 0);
        }
    }

    // C layout: col = lane&15, row = (lane>>4)*4 + j (+ mt*16). Write packed y table.
    #pragma unroll
    for (int mt = 0; mt < 4; ++mt) {
        #pragma unroll
        for (int j = 0; j < 4; ++j) {
            int r = base + mt * 16 + l4 * 4 + j;
            float o = fmaxf((*accp[mt])[j] + bias_v, 0.0f);
            float wsc = (r < NNODE) ? wout[r] : 0.0f;
            float oy = o * wsc;
            float oyn = __shfl_xor(oy, 1);
            if (((l15 & 1) == 0) && r < NNODE)
                otab[(size_t)r * 32 + ((n0 + l15) >> 1)] = packbf(oy, oyn);
        }
    }
}

// ---------------- scoring + loss ----------------
// Each wave grid-strides over samples (8 per wave); one atomicAdd per block.

__global__ __launch_bounds__(256) void score_kernel(
    const int* __restrict__ user, const int* __restrict__ item_i,
    const int* __restrict__ item_j,
    const float* __restrict__ eu, const float* __restrict__ ei,
    const uint32* __restrict__ y1b2, const uint32* __restrict__ y2b,
    const float* __restrict__ sback,
    float* __restrict__ out, int B, int nwaves)
{
    int tid = threadIdx.x;
    int lane = tid & 63;
    int wv = tid >> 6;
    int gw = blockIdx.x * 4 + wv;
    int h = lane >> 5, d2 = lane & 31;

    float spacc = 0.0f;
    for (int w = gw; w < B; w += nwaves) {
        int u  = user[w];
        int i0 = item_i[w];
        int j0 = item_j[w];
        int ii = USER_NUM + i0;
        int jj = USER_NUM + j0;

        float e0u = eu[(size_t)u  * DDIM + lane];
        float e0i = ei[(size_t)i0 * DDIM + lane];
        float e0j = ei[(size_t)j0 * DDIM + lane];
        float di = e0u * e0i;
        float dj = e0u * e0j;

        const uint32* tb = h ? y2b : y1b2;
        float su = sback[u], si2 = sback[ii], sj2 = sback[jj];
        uint32 wu = tb[(size_t)u  * 32 + d2];
        uint32 wi = tb[(size_t)ii * 32 + d2];
        uint32 wj = tb[(size_t)jj * 32 + d2];
        float u0 = __uint_as_float(wu << 16) * su,   u1 = __uint_as_float(wu & 0xffff0000u) * su;
        float i0f = __uint_as_float(wi << 16) * si2, i1f = __uint_as_float(wi & 0xffff0000u) * si2;
        float j0f = __uint_as_float(wj << 16) * sj2, j1f = __uint_as_float(wj & 0xffff0000u) * sj2;
        di += u0 * i0f + u1 * i1f;
        dj += u0 * j0f + u1 * j1f;

        for (int off = 32; off; off >>= 1) {
            di += __shfl_xor(di, off);
            dj += __shfl_xor(dj, off);
        }
        if (lane == 0) {
            out[w] = di;
            out[B + w] = dj;
            float x = di - dj;
            spacc += fmaxf(-x, 0.0f) + log1pf(expf(-fabsf(x)));   // softplus(-x)
        }
    }

    __shared__ float sred[4];
    if (lane == 0) sred[wv] = spacc;
    __syncthreads();
    if (tid == 0)
        atomicAdd(&out[2 * B], sred[0] + sred[1] + sred[2] + sred[3]);
}

// ---------------- launch ----------------

extern "C" void kernel_launch(void* const* d_in, const int* in_sizes, int n_in,
                              void* d_out, int out_size, void* d_ws, size_t ws_size,
                              hipStream_t stream) {
    const int*   user       = (const int*)d_in[0];
    const int*   item_i     = (const int*)d_in[1];
    const int*   item_j     = (const int*)d_in[2];
    const int*   rows       = (const int*)d_in[3];
    const int*   cols       = (const int*)d_in[4];
    const float* embed_user = (const float*)d_in[6];
    const float* embed_item = (const float*)d_in[7];
    const float* W1  = (const float*)d_in[8];
    const float* b1  = (const float*)d_in[9];
    const float* Wi1 = (const float*)d_in[10];
    const float* bi1 = (const float*)d_in[11];
    const float* W2  = (const float*)d_in[12];
    const float* b2  = (const float*)d_in[13];
    const float* Wi2 = (const float*)d_in[14];
    const float* bi2 = (const float*)d_in[15];

    int B = in_sizes[0];
    int E = in_sizes[3];
    float* out = (float*)d_out;

    char* ws = (char*)d_ws;
    size_t off = 0;
    auto alloc = [&](size_t bytes) -> void* {
        void* p = ws + off;
        off += (bytes + 255) & ~(size_t)255;
        return p;
    };
    uint32* y1b      = (uint32*)alloc((size_t)(NNODE + 1) * 32 * 4);   // 18.5 MB
    uint32* y1b2     = (uint32*)alloc((size_t)(NNODE + 1) * 32 * 4);
    uint32* y2b      = (uint32*)alloc((size_t)(NNODE + 1) * 32 * 4);
    int*    row_ptr  = (int*)alloc((size_t)(NNODE + 1) * 4);
    int*    csr_col  = (int*)alloc((size_t)E * 4);
    uint32* staged   = (uint32*)alloc((size_t)E * 4);
    float*  dinv     = (float*)alloc((size_t)NNODE * 4);
    float*  wout     = (float*)alloc((size_t)NNODE * 4);
    float*  sback    = (float*)alloc((size_t)NNODE * 4);
    int*    totals   = (int*)alloc((size_t)NBUCK * 4);
    int*    bucket_off = (int*)alloc((size_t)(NBUCK + 1) * 4);
    int     nblocks  = (E + EPB - 1) / EPB;            // 245
    int*    blkcnt   = (int*)alloc((size_t)nblocks * NBUCK * 4);

    bucket_count_kernel<<<nblocks, 1024, 0, stream>>>(rows, blkcnt, E);
    bucket_block_scan_kernel<<<NBUCK, 256, 0, stream>>>(blkcnt, totals, nblocks);
    bucket_off_kernel<<<1, 1024, 0, stream>>>(totals, bucket_off, row_ptr, E);
    stage_kernel<<<nblocks, 1024, 0, stream>>>(rows, cols, blkcnt, bucket_off, staged, E);
    build_kernel<<<NBUCK, 256, 0, stream>>>(staged, bucket_off, row_ptr, csr_col,
                                            dinv, wout, sback);

    pack1_kernel<<<((NNODE + 1) * 32 + 255) / 256, 256, 0, stream>>>(
        embed_user, embed_item, wout, y1b, y1b2, y2b);

    const int GNNB = (NNODE + 63) / 64;   // 2254
    gnn_layer_kernel<<<GNNB, 256, 0, stream>>>(
        y1b, row_ptr, csr_col, sback, dinv, wout, W1, b1, Wi1, bi1, y1b2);
    gnn_layer_kernel<<<GNNB, 256, 0, stream>>>(
        y1b2, row_ptr, csr_col, sback, dinv, wout, W2, b2, Wi2, bi2, y2b);

    init_loss_kernel<<<1, 64, 0, stream>>>(out, 2 * B);
    const int SCORE_BLOCKS = 256;                      // 1024 waves, 8 samples each
    score_kernel<<<SCORE_BLOCKS, 256, 0, stream>>>(
        user, item_i, item_j, embed_user, embed_item, y1b2, y2b, sback,
        out, B, SCORE_BLOCKS * 4);
}